// Round 20
// baseline (259.181 us; speedup 1.0000x reference)
//
#include <hip/hip_runtime.h>
#include <stdint.h>

// Pipeline: cvt(fp32->bf16, + RoPE tables)
//   -> gemm_qk: x@[Wq;Wk] -> Q,K [BH][S][128], RoPE fused in epilogue.
//      512 blocks of 128x256 tiles, 2-deep ring (48KB) -> 2 blocks/CU co-resident in ONE
//      round (m114 overlap covers the per-tile vmcnt(0) drain). Pair bid/bid+256 shares
//      XCD AND A-rows. Rope exchange (col d^64 = wave w^1) through dead Bs ring (32KB —
//      R19 BUG FIX: As is only 16KB, exchange overflowed it; Bs is exactly 32KB).
//   -> gemm_v : x@Wv -> V^T [BH][128][S] (grid 256 = one round)
//   -> attn_fwd (R14 exact, 99-100us floor): QBLK=64, 4 waves, pairs (p,31-p),
//      grid (bh=32,pair=16)=512, 75KB LDS -> 2 blocks/CU, XCD-aligned, counted vmcnt,
//      defer-max; Q pre-roped+scaled.
//   -> gemm_o : out-proj on deep 128x256 engine, fp32 epilogue, grid 256 = one round.

#define SCALE_Q 0.08838834764831845f

typedef short bf16x8 __attribute__((ext_vector_type(8)));
typedef float f32x4 __attribute__((ext_vector_type(4)));
typedef unsigned short u16x4v __attribute__((ext_vector_type(4)));
typedef unsigned short u16x8v __attribute__((ext_vector_type(8)));

__device__ __forceinline__ unsigned short f2bf(float f) {
  unsigned u = __float_as_uint(f);
  return (unsigned short)((u + 0x7FFFu + ((u >> 16) & 1u)) >> 16);  // RNE
}
__device__ __forceinline__ float bf2f(unsigned short h) {
  return __uint_as_float(((unsigned)h) << 16);
}
__device__ __forceinline__ void gld16(void* lds, const void* g) {
  __builtin_amdgcn_global_load_lds(
      (const __attribute__((address_space(1))) unsigned int*)g,
      (__attribute__((address_space(3))) unsigned int*)lds, 16, 0, 0);
}

// -------- fp32 -> bf16 conversion (regions 0-4) + RoPE tables (region 5) --------
__global__ __launch_bounds__(256) void cvt_all(
    const float* __restrict__ x, const float* __restrict__ wq,
    const float* __restrict__ wk, const float* __restrict__ wv,
    const float* __restrict__ wo,
    unsigned short* __restrict__ xb, unsigned short* __restrict__ wqkv,
    unsigned short* __restrict__ wob,
    float* __restrict__ ct, float* __restrict__ st) {
  int r = blockIdx.y;
  if (r == 5) {  // ct/st[s*64+j] = cos/sin(s * 10000^(-j/64))
    int id = blockIdx.x * 256 + threadIdx.x;
    if (id < 131072) {
      int s = id >> 6, j = id & 63;
      float inv = __powf(10000.0f, -(float)j * (1.0f / 64.0f));
      float a = (float)s * inv;
      ct[id] = __cosf(a);
      st[id] = __sinf(a);
    }
    return;
  }
  size_t i = ((size_t)blockIdx.x * 256 + threadIdx.x) * 8;
  const float* src; unsigned short* dst; size_t n;
  if (r == 0)      { src = x;  dst = xb;             n = 8388608; }
  else if (r == 1) { src = wq; dst = wqkv;           n = 4194304; }
  else if (r == 2) { src = wk; dst = wqkv + 4194304; n = 4194304; }
  else if (r == 3) { src = wv; dst = wqkv + 8388608; n = 4194304; }
  else             { src = wo; dst = wob;            n = 4194304; }
  if (i >= n) return;
  float4 a = *(const float4*)(src + i);
  float4 b = *(const float4*)(src + i + 4);
  u16x8v o;
  o[0] = f2bf(a.x); o[1] = f2bf(a.y); o[2] = f2bf(a.z); o[3] = f2bf(a.w);
  o[4] = f2bf(b.x); o[5] = f2bf(b.y); o[6] = f2bf(b.z); o[7] = f2bf(b.w);
  *(u16x8v*)(dst + i) = o;
}

// ---------------- gemm_qk: 128x256x32, 2-deep ring (48KB), grid 512, 2 blocks/CU --------
// A [4096][2048] @ B[4096][2048]^T; cols 0-2047 -> Q, 2048-4095 -> K (RoPE fused).
// 512 threads, 8 waves (wm 0..1, wn 0..3), wave tile 64x64, acc[4][4].
// A-LDS 8KB/buf packed [64 ldsrows][128B] (ldsrow L = A-rows L,L+64); B-LDS 16KB/buf
// [128 ldsrows][128B] (ldsrow L = B-rows L,L+128); swz phys slot ^ (L&7).
// Grid: chunk=bid&7 owns rows chunk*4..+3 x all 16 cols; pair bid/bid+256 = same XCD,
// same A-rows. Per-tile vmcnt(0) drain covered by partner block.
__global__ __launch_bounds__(512, 4) void gemm_qk(
    const unsigned short* __restrict__ A, const unsigned short* __restrict__ B,
    unsigned short* __restrict__ Qo, unsigned short* __restrict__ Ko, int Kd,
    const float* __restrict__ ctab, const float* __restrict__ stab) {
  __shared__ unsigned short As[2][64 * 64];    // 2 x 8KB
  __shared__ unsigned short Bs[2][128 * 64];   // 2 x 16KB
  const int t = threadIdx.x;
  const int lane = t & 63, w = t >> 6;
  const int g = lane >> 4, c15 = lane & 15;
  const int wm = w >> 2, wn = w & 3;

  const int chunk = (int)blockIdx.x & 7;
  const int idx = (int)blockIdx.x >> 3;       // 0..63
  const int row = chunk * 4 + (idx & 3);
  const int col = idx >> 2;                   // 0..15
  const int brow = row * 128, bcol = col * 256;

  const int l = t >> 3;
  const int lg = (t & 7) ^ (l & 7);
  const unsigned short* srcA = A + (size_t)(brow + l + ((lg >> 2) << 6)) * Kd + (lg & 3) * 8;
  const unsigned short* srcB = B + (size_t)(bcol + l + ((lg >> 2) << 7)) * Kd + (lg & 3) * 8;

  auto stage = [&](int kt) {
    const int buf = kt & 1;
    const unsigned short* a = srcA + kt * 32;
    const unsigned short* b = srcB + kt * 32;
    gld16((char*)As[buf] + t * 16, a);
    gld16((char*)Bs[buf] + t * 16, b);
    gld16((char*)Bs[buf] + 8192 + t * 16, b + (size_t)64 * Kd);
  };

  const int aoff = c15 * 128 + ((((wm << 2) | g) ^ (c15 & 7)) << 4);
  const int boff = ((wn & 1) << 13) + c15 * 128 + (((((wn >> 1) << 2) | g) ^ (c15 & 7)) << 4);

  f32x4 zero4 = {0.f, 0.f, 0.f, 0.f};
  f32x4 acc[4][4];
#pragma unroll
  for (int a_ = 0; a_ < 4; ++a_)
#pragma unroll
    for (int b_ = 0; b_ < 4; ++b_) acc[a_][b_] = zero4;

  const int nk = Kd >> 5;  // 64
  stage(0);
  asm volatile("s_waitcnt vmcnt(0)" ::: "memory");
  __builtin_amdgcn_s_barrier();

  for (int kt = 0; kt < nk; ++kt) {
    const char* ab = (const char*)As[kt & 1];
    const char* bb = (const char*)Bs[kt & 1];
    bf16x8 bfv[4], af0[2], af1[2];
#pragma unroll
    for (int nj = 0; nj < 4; ++nj) bfv[nj] = *(const bf16x8*)(bb + boff + nj * 2048);
#pragma unroll
    for (int mi = 0; mi < 2; ++mi) af0[mi] = *(const bf16x8*)(ab + aoff + mi * 2048);
    __builtin_amdgcn_sched_barrier(0);
#pragma unroll
    for (int mi = 0; mi < 2; ++mi) af1[mi] = *(const bf16x8*)(ab + aoff + (mi + 2) * 2048);
    if (kt + 1 < nk) stage(kt + 1);             // writes buf[kt^1], whose reads closed @kt-1
    asm volatile("s_waitcnt lgkmcnt(2)" ::: "memory");
    __builtin_amdgcn_sched_barrier(0);
    __builtin_amdgcn_s_setprio(1);
#pragma unroll
    for (int mi = 0; mi < 2; ++mi)
#pragma unroll
      for (int nj = 0; nj < 4; ++nj)
        acc[mi][nj] = __builtin_amdgcn_mfma_f32_16x16x32_bf16(
            af0[mi], bfv[nj], acc[mi][nj], 0, 0, 0);
    __builtin_amdgcn_s_setprio(0);
    asm volatile("s_waitcnt lgkmcnt(0)" ::: "memory");
    __builtin_amdgcn_sched_barrier(0);
    __builtin_amdgcn_s_setprio(1);
#pragma unroll
    for (int mi = 0; mi < 2; ++mi)
#pragma unroll
      for (int nj = 0; nj < 4; ++nj)
        acc[mi + 2][nj] = __builtin_amdgcn_mfma_f32_16x16x32_bf16(
            af1[mi], bfv[nj], acc[mi + 2][nj], 0, 0, 0);
    __builtin_amdgcn_s_setprio(0);
    asm volatile("s_waitcnt vmcnt(0)" ::: "memory");   // buf[kt+1] landed (m97 drain;
    __builtin_amdgcn_s_barrier();                      //  covered by co-resident block)
  }

  // Epilogue with fused RoPE: partner col d^64 = same lane, wave w^1.
  // Exchange through DEAD Bs ring: 2x16KB = exactly 32KB = [8 w][4 nj][4 i][64 lane] fp32.
  float* xch = (float*)Bs;
#pragma unroll
  for (int mi = 0; mi < 4; ++mi) {
#pragma unroll
    for (int nj = 0; nj < 4; ++nj)
#pragma unroll
      for (int i = 0; i < 4; ++i)
        xch[w * 1024 + nj * 256 + i * 64 + lane] = acc[mi][nj][i];
    asm volatile("s_waitcnt lgkmcnt(0)" ::: "memory");
    __builtin_amdgcn_s_barrier();               // slice visible to partner wave
    int row0 = brow + wm * 64 + mi * 16 + g * 4;
    int s0 = row0 & 2047;
#pragma unroll
    for (int nj = 0; nj < 4; ++nj) {
      int colc = bcol + wn * 64 + nj * 16 + c15;
      int which = colc >> 11;           // 0=Q 1=K
      int hc = colc & 2047;
      int bh = ((row0 >> 11) << 4) + (hc >> 7);
      int d = hc & 127;
      int j6 = d & 63;
      float sgn = (d & 64) ? 1.0f : -1.0f;   // out_lo = v*c - hi*s ; out_hi = v*c + lo*s
      float scl = which ? 1.0f : SCALE_Q;
      unsigned short* dst = (which ? Ko : Qo) + ((size_t)bh * 2048 + s0) * 128 + d;
#pragma unroll
      for (int i = 0; i < 4; ++i) {
        float c = ctab[(size_t)(s0 + i) * 64 + j6];
        float sn = stab[(size_t)(s0 + i) * 64 + j6];
        float v = acc[mi][nj][i];
        float pv = xch[(w ^ 1) * 1024 + nj * 256 + i * 64 + lane];
        dst[(size_t)i * 128] = f2bf((v * c + sgn * pv * sn) * scl);
      }
    }
    asm volatile("s_waitcnt lgkmcnt(0)" ::: "memory");
    __builtin_amdgcn_s_barrier();               // reads done before next slice overwrite
  }
}

// ---------------- gemm_v: 128x256x32, 4-deep ring (96KB), grid 32x8=256 ----------------
__global__ __launch_bounds__(512, 2) void gemm_v(
    const unsigned short* __restrict__ A, const unsigned short* __restrict__ B,
    unsigned short* __restrict__ Vt, int Kd) {
  __shared__ unsigned short As[4][64 * 64];    // 4 x 8KB
  __shared__ unsigned short Bs[4][128 * 64];   // 4 x 16KB
  const int t = threadIdx.x;
  const int lane = t & 63, w = t >> 6;
  const int g = lane >> 4, c15 = lane & 15;
  const int wm = w >> 2, wn = w & 3;

  const int chunk = (int)blockIdx.x & 7;
  const int idx = (int)blockIdx.x >> 3;       // 0..31
  const int row = chunk * 4 + (idx >> 3);
  const int col = idx & 7;
  const int brow = row * 128, bcol = col * 256;

  const int l = t >> 3;
  const int lg = (t & 7) ^ (l & 7);
  const unsigned short* srcA = A + (size_t)(brow + l + ((lg >> 2) << 6)) * Kd + (lg & 3) * 8;
  const unsigned short* srcB = B + (size_t)(bcol + l + ((lg >> 2) << 7)) * Kd + (lg & 3) * 8;

  auto stage = [&](int kt) {
    const int buf = kt & 3;
    const unsigned short* a = srcA + kt * 32;
    const unsigned short* b = srcB + kt * 32;
    gld16((char*)As[buf] + t * 16, a);
    gld16((char*)Bs[buf] + t * 16, b);
    gld16((char*)Bs[buf] + 8192 + t * 16, b + (size_t)64 * Kd);
  };

  const int aoff = c15 * 128 + ((((wm << 2) | g) ^ (c15 & 7)) << 4);
  const int boff = ((wn & 1) << 13) + c15 * 128 + (((((wn >> 1) << 2) | g) ^ (c15 & 7)) << 4);

  f32x4 zero4 = {0.f, 0.f, 0.f, 0.f};
  f32x4 acc[4][4];
#pragma unroll
  for (int a_ = 0; a_ < 4; ++a_)
#pragma unroll
    for (int b_ = 0; b_ < 4; ++b_) acc[a_][b_] = zero4;

  const int nk = Kd >> 5;  // 64
  stage(0); stage(1); stage(2);
  asm volatile("s_waitcnt vmcnt(6)" ::: "memory");
  __builtin_amdgcn_s_barrier();

  for (int kt = 0; kt < nk; ++kt) {
    const char* ab = (const char*)As[kt & 3];
    const char* bb = (const char*)Bs[kt & 3];
    bf16x8 bfv[4], af0[2], af1[2];
#pragma unroll
    for (int nj = 0; nj < 4; ++nj) bfv[nj] = *(const bf16x8*)(bb + boff + nj * 2048);
#pragma unroll
    for (int mi = 0; mi < 2; ++mi) af0[mi] = *(const bf16x8*)(ab + aoff + mi * 2048);
    __builtin_amdgcn_sched_barrier(0);
#pragma unroll
    for (int mi = 0; mi < 2; ++mi) af1[mi] = *(const bf16x8*)(ab + aoff + (mi + 2) * 2048);
    if (kt + 3 < nk) stage(kt + 3);
    asm volatile("s_waitcnt lgkmcnt(2)" ::: "memory");
    __builtin_amdgcn_sched_barrier(0);
    __builtin_amdgcn_s_setprio(1);
#pragma unroll
    for (int mi = 0; mi < 2; ++mi)
#pragma unroll
      for (int nj = 0; nj < 4; ++nj)
        acc[mi][nj] = __builtin_amdgcn_mfma_f32_16x16x32_bf16(
            af0[mi], bfv[nj], acc[mi][nj], 0, 0, 0);
    __builtin_amdgcn_s_setprio(0);
    asm volatile("s_waitcnt lgkmcnt(0)" ::: "memory");
    __builtin_amdgcn_sched_barrier(0);
    __builtin_amdgcn_s_setprio(1);
#pragma unroll
    for (int mi = 0; mi < 2; ++mi)
#pragma unroll
      for (int nj = 0; nj < 4; ++nj)
        acc[mi + 2][nj] = __builtin_amdgcn_mfma_f32_16x16x32_bf16(
            af1[mi], bfv[nj], acc[mi + 2][nj], 0, 0, 0);
    __builtin_amdgcn_s_setprio(0);
    if (kt + 3 < nk) {
      asm volatile("s_waitcnt vmcnt(6)" ::: "memory");
    } else if (kt + 3 == nk) {
      asm volatile("s_waitcnt vmcnt(3)" ::: "memory");
    } else if (kt + 2 == nk) {
      asm volatile("s_waitcnt vmcnt(0)" ::: "memory");
    }
    __builtin_amdgcn_s_barrier();
  }

#pragma unroll
  for (int mi = 0; mi < 4; ++mi) {
#pragma unroll
    for (int nj = 0; nj < 4; ++nj) {
      f32x4 v = acc[mi][nj];
      int row0 = brow + wm * 64 + mi * 16 + g * 4;
      int colc = bcol + wn * 64 + nj * 16 + c15;
      int bh = ((row0 >> 11) << 4) + (colc >> 7);
      int d = colc & 127, s0 = row0 & 2047;
      u16x4v pk;
      pk[0] = f2bf(v[0]); pk[1] = f2bf(v[1]); pk[2] = f2bf(v[2]); pk[3] = f2bf(v[3]);
      *(u16x4v*)(Vt + ((size_t)bh * 128 + d) * 2048 + s0) = pk;
    }
  }
}

// ---------------- gemm_o: out-proj, 128x256x32 deep ring, fp32 epilogue, grid 256 -------
__global__ __launch_bounds__(512, 2) void gemm_o(
    const unsigned short* __restrict__ A, const unsigned short* __restrict__ B,
    float* __restrict__ C, int N, int Kd) {
  __shared__ unsigned short As[4][64 * 64];    // 4 x 8KB
  __shared__ unsigned short Bs[4][128 * 64];   // 4 x 16KB
  const int t = threadIdx.x;
  const int lane = t & 63, w = t >> 6;
  const int g = lane >> 4, c15 = lane & 15;
  const int wm = w >> 2, wn = w & 3;

  const int chunk = (int)blockIdx.x & 7;
  const int idx = (int)blockIdx.x >> 3;       // 0..31
  const int row = chunk * 4 + (idx >> 3);
  const int col = idx & 7;
  const int brow = row * 128, bcol = col * 256;

  const int l = t >> 3;
  const int lg = (t & 7) ^ (l & 7);
  const unsigned short* srcA = A + (size_t)(brow + l + ((lg >> 2) << 6)) * Kd + (lg & 3) * 8;
  const unsigned short* srcB = B + (size_t)(bcol + l + ((lg >> 2) << 7)) * Kd + (lg & 3) * 8;

  auto stage = [&](int kt) {
    const int buf = kt & 3;
    const unsigned short* a = srcA + kt * 32;
    const unsigned short* b = srcB + kt * 32;
    gld16((char*)As[buf] + t * 16, a);
    gld16((char*)Bs[buf] + t * 16, b);
    gld16((char*)Bs[buf] + 8192 + t * 16, b + (size_t)64 * Kd);
  };

  const int aoff = c15 * 128 + ((((wm << 2) | g) ^ (c15 & 7)) << 4);
  const int boff = ((wn & 1) << 13) + c15 * 128 + (((((wn >> 1) << 2) | g) ^ (c15 & 7)) << 4);

  f32x4 zero4 = {0.f, 0.f, 0.f, 0.f};
  f32x4 acc[4][4];
#pragma unroll
  for (int a_ = 0; a_ < 4; ++a_)
#pragma unroll
    for (int b_ = 0; b_ < 4; ++b_) acc[a_][b_] = zero4;

  const int nk = Kd >> 5;  // 64
  stage(0); stage(1); stage(2);
  asm volatile("s_waitcnt vmcnt(6)" ::: "memory");
  __builtin_amdgcn_s_barrier();

  for (int kt = 0; kt < nk; ++kt) {
    const char* ab = (const char*)As[kt & 3];
    const char* bb = (const char*)Bs[kt & 3];
    bf16x8 bfv[4], af0[2], af1[2];
#pragma unroll
    for (int nj = 0; nj < 4; ++nj) bfv[nj] = *(const bf16x8*)(bb + boff + nj * 2048);
#pragma unroll
    for (int mi = 0; mi < 2; ++mi) af0[mi] = *(const bf16x8*)(ab + aoff + mi * 2048);
    __builtin_amdgcn_sched_barrier(0);
#pragma unroll
    for (int mi = 0; mi < 2; ++mi) af1[mi] = *(const bf16x8*)(ab + aoff + (mi + 2) * 2048);
    if (kt + 3 < nk) stage(kt + 3);
    asm volatile("s_waitcnt lgkmcnt(2)" ::: "memory");
    __builtin_amdgcn_sched_barrier(0);
    __builtin_amdgcn_s_setprio(1);
#pragma unroll
    for (int mi = 0; mi < 2; ++mi)
#pragma unroll
      for (int nj = 0; nj < 4; ++nj)
        acc[mi][nj] = __builtin_amdgcn_mfma_f32_16x16x32_bf16(
            af0[mi], bfv[nj], acc[mi][nj], 0, 0, 0);
    __builtin_amdgcn_s_setprio(0);
    asm volatile("s_waitcnt lgkmcnt(0)" ::: "memory");
    __builtin_amdgcn_sched_barrier(0);
    __builtin_amdgcn_s_setprio(1);
#pragma unroll
    for (int mi = 0; mi < 2; ++mi)
#pragma unroll
      for (int nj = 0; nj < 4; ++nj)
        acc[mi + 2][nj] = __builtin_amdgcn_mfma_f32_16x16x32_bf16(
            af1[mi], bfv[nj], acc[mi + 2][nj], 0, 0, 0);
    __builtin_amdgcn_s_setprio(0);
    if (kt + 3 < nk) {
      asm volatile("s_waitcnt vmcnt(6)" ::: "memory");
    } else if (kt + 3 == nk) {
      asm volatile("s_waitcnt vmcnt(3)" ::: "memory");
    } else if (kt + 2 == nk) {
      asm volatile("s_waitcnt vmcnt(0)" ::: "memory");
    }
    __builtin_amdgcn_s_barrier();
  }

#pragma unroll
  for (int mi = 0; mi < 4; ++mi) {
#pragma unroll
    for (int nj = 0; nj < 4; ++nj) {
      f32x4 v = acc[mi][nj];
      int row0 = brow + wm * 64 + mi * 16 + g * 4;
      int colc = bcol + wn * 64 + nj * 16 + c15;
#pragma unroll
      for (int i = 0; i < 4; ++i) C[(size_t)(row0 + i) * N + colc] = v[i];
    }
  }
}

// ---------------- attn_fwd (R14 exact; Q pre-roped+scaled by gemm_qk epilogue) ----------
__global__ __launch_bounds__(256, 2) void attn_fwd(
    const unsigned short* __restrict__ Qg, const unsigned short* __restrict__ Kg,
    const unsigned short* __restrict__ Vtg, unsigned short* __restrict__ Og) {
  __shared__ unsigned short Ks[2][64 * 128];   // [kv64][d128] 256B rows, swz ^(row&15)
  __shared__ unsigned short Vs[2][128 * 64];   // [d128][kv64] 128B rows, swz ^(row&7)
  __shared__ unsigned short Pl[4][16 * 88];    // per-wave P buffer
  const int t = threadIdx.x;
  const int lane = t & 63, w = t >> 6;         // w 0..3
  const int g = lane >> 4, c15 = lane & 15;
  const int bh = blockIdx.x;                   // 0..31 -> bid%8 = bh%8 = XCD
  const int pair = blockIdx.y;                 // 0..15
  const int b = bh >> 4, h = bh & 15;

  const int ksrow = t >> 4;                    // 0..15
  const int kssl = (t & 15) ^ (ksrow & 15);
  const unsigned short* kp = Kg + ((size_t)bh * 2048 + ksrow) * 128 + kssl * 8;
  const int vsrow = t >> 3;                    // 0..31
  const int vssl = (t & 7) ^ (vsrow & 7);
  const unsigned short* vp = Vtg + ((size_t)bh * 128 + vsrow) * 2048 + vssl * 8;

  auto stageTile = [&](int buf, int tkv) {     // 8 gld16/thread = 32KB total
#pragma unroll
    for (int c = 0; c < 4; ++c) {
      gld16((char*)Ks[buf] + c * 4096 + t * 16, kp + (size_t)(tkv * 64 + c * 16) * 128);
      gld16((char*)Vs[buf] + c * 4096 + t * 16, vp + (size_t)c * 32 * 2048 + tkv * 64);
    }
  };

  f32x4 zero4 = {0.f, 0.f, 0.f, 0.f};
  f32x4 o[8];
  float mrow[4], lrow[4];
  bf16x8 qf[4];

  auto loadQ = [&](int qb) {
    const unsigned short* qp =
        Qg + ((size_t)bh * 2048 + qb * 64 + w * 16 + c15) * 128 + g * 8;
#pragma unroll
    for (int kf = 0; kf < 4; ++kf) qf[kf] = *(const bf16x8*)(qp + kf * 32);
#pragma unroll
    for (int db = 0; db < 8; ++db) o[db] = zero4;
#pragma unroll
    for (int i = 0; i < 4; ++i) { mrow[i] = -1e30f; lrow[i] = 0.f; }
  };

  auto computeTile = [&](int buf, int qb, int tkv) {
    const int qrow = qb * 64 + w * 16;
    f32x4 sv[4];
    __builtin_amdgcn_s_setprio(1);
#pragma unroll
    for (int cb2 = 0; cb2 < 4; ++cb2) {
      f32x4 z = zero4;
#pragma unroll
      for (int kf = 0; kf < 4; ++kf) {
        int rowk = cb2 * 16 + c15;
        int p = (kf * 4 + g) ^ c15;
        bf16x8 kfr = *(const bf16x8*)((const char*)Ks[buf] + rowk * 256 + p * 16);
        z = __builtin_amdgcn_mfma_f32_16x16x32_bf16(qf[kf], kfr, z, 0, 0, 0);
      }
      sv[cb2] = z;
    }
    __builtin_amdgcn_s_setprio(0);
    if (tkv == qb) {  // diagonal tile causal mask
#pragma unroll
      for (int cb2 = 0; cb2 < 4; ++cb2)
#pragma unroll
        for (int i = 0; i < 4; ++i) {
          int colk = tkv * 64 + cb2 * 16 + c15;
          int rq = qrow + g * 4 + i;
          if (colk > rq) sv[cb2][i] = -1e30f;
        }
    }
    float pmx[4];
#pragma unroll
    for (int i = 0; i < 4; ++i)
      pmx[i] = fmaxf(fmaxf(sv[0][i], sv[1][i]), fmaxf(sv[2][i], sv[3][i]));
#pragma unroll
    for (int dd = 1; dd < 16; dd <<= 1)
#pragma unroll
      for (int i = 0; i < 4; ++i) pmx[i] = fmaxf(pmx[i], __shfl_xor(pmx[i], dd));
    int grow = 0;
#pragma unroll
    for (int i = 0; i < 4; ++i) grow |= (pmx[i] > mrow[i] + 8.0f) ? 1 : 0;
    if (__any(grow)) {  // defer-max (T13)
#pragma unroll
      for (int i = 0; i < 4; ++i) {
        float nm = fmaxf(mrow[i], pmx[i]);
        float sc = __expf(mrow[i] - nm);
        mrow[i] = nm;
        lrow[i] *= sc;
#pragma unroll
        for (int db = 0; db < 8; ++db) o[db][i] *= sc;
      }
    }
    float psum[4] = {0.f, 0.f, 0.f, 0.f};
#pragma unroll
    for (int cb2 = 0; cb2 < 4; ++cb2)
#pragma unroll
      for (int i = 0; i < 4; ++i) {
        float e = __expf(sv[cb2][i] - mrow[i]);
        sv[cb2][i] = e;
        psum[i] += e;
      }
#pragma unroll
    for (int dd = 1; dd < 16; dd <<= 1)
#pragma unroll
      for (int i = 0; i < 4; ++i) psum[i] += __shfl_xor(psum[i], dd);
#pragma unroll
    for (int i = 0; i < 4; ++i) lrow[i] += psum[i];

    unsigned short* pw = &Pl[w][0];
#pragma unroll
    for (int cb2 = 0; cb2 < 4; ++cb2)
#pragma unroll
      for (int i = 0; i < 4; ++i)
        pw[(g * 4 + i) * 88 + cb2 * 16 + c15] = f2bf(sv[cb2][i]);
    bf16x8 pf[2];
#pragma unroll
    for (int kb = 0; kb < 2; ++kb)
      pf[kb] = *(const bf16x8*)((const char*)pw + c15 * 176 + kb * 64 + g * 16);

    __builtin_amdgcn_s_setprio(1);
#pragma unroll
    for (int db = 0; db < 8; ++db) {
#pragma unroll
      for (int kb = 0; kb < 2; ++kb) {
        int rowv = db * 16 + c15;
        int p = (kb * 4 + g) ^ (c15 & 7);
        bf16x8 vfr = *(const bf16x8*)((const char*)Vs[buf] + rowv * 128 + p * 16);
        o[db] = __builtin_amdgcn_mfma_f32_16x16x32_bf16(pf[kb], vfr, o[db], 0, 0, 0);
      }
    }
    __builtin_amdgcn_s_setprio(0);
  };

  auto writeO = [&](int qb) {
    float linv[4];
#pragma unroll
    for (int i = 0; i < 4; ++i) linv[i] = 1.0f / lrow[i];
#pragma unroll
    for (int db = 0; db < 8; ++db)
#pragma unroll
      for (int i = 0; i < 4; ++i) {
        int q = qb * 64 + w * 16 + g * 4 + i;
        Og[((size_t)(b * 2048 + q)) * 2048 + h * 128 + db * 16 + c15] =
            f2bf(o[db][i] * linv[i]);
      }
  };

  const int qbA = pair, qbB = 31 - pair;       // 64-row q-blocks
  const int ntA = qbA + 1, ntB = qbB + 1;      // 33 tiles total, uniform
  int cur = 0;

  stageTile(0, 0);
  loadQ(qbA);
  for (int tkv = 0; tkv < ntA; ++tkv) {
    if (tkv + 1 < ntA) stageTile(cur ^ 1, tkv + 1);
    else               stageTile(cur ^ 1, 0);          // first tile of half B
    asm volatile("s_waitcnt vmcnt(8)" ::: "memory");   // current buf landed
    __builtin_amdgcn_s_barrier();
    computeTile(cur, qbA, tkv);
    __builtin_amdgcn_s_barrier();                      // close reads of buf[cur]
    cur ^= 1;
  }
  writeO(qbA);
  loadQ(qbB);
  for (int tkv = 0; tkv < ntB; ++tkv) {
    if (tkv + 1 < ntB) {
      stageTile(cur ^ 1, tkv + 1);
      asm volatile("s_waitcnt vmcnt(8)" ::: "memory");
    } else {
      asm volatile("s_waitcnt vmcnt(0)" ::: "memory");
    }
    __builtin_amdgcn_s_barrier();
    computeTile(cur, qbB, tkv);
    __builtin_amdgcn_s_barrier();
    cur ^= 1;
  }
  writeO(qbB);
}

extern "C" void kernel_launch(void* const* d_in, const int* in_sizes, int n_in,
                              void* d_out, int out_size, void* d_ws, size_t ws_size,
                              hipStream_t stream) {
  const float* x  = (const float*)d_in[0];
  const float* Wq = (const float*)d_in[1];
  const float* Wk = (const float*)d_in[2];
  const float* Wv = (const float*)d_in[3];
  const float* Wo = (const float*)d_in[4];
  char* p = (char*)d_ws;
  unsigned short* xb    = (unsigned short*)p;                 // 16 MB (reused as Ao)
  unsigned short* wqkvb = (unsigned short*)(p + 16777216);    // 24 MB
  unsigned short* wob   = (unsigned short*)(p + 41943040);    //  8 MB
  unsigned short* Qb    = (unsigned short*)(p + 50331648);    // 16 MB
  unsigned short* Kb    = (unsigned short*)(p + 67108864);    // 16 MB
  unsigned short* Vt    = (unsigned short*)(p + 83886080);    // 16 MB
  float* ctab           = (float*)(p + 100663296);            // 0.5 MB
  float* stab           = (float*)(p + 101187584);            // 0.5 MB -> end 101711872
  unsigned short* Ao = xb;  // xb dead after QKV gemms

  cvt_all<<<dim3(4096, 6), 256, 0, stream>>>(x, Wq, Wk, Wv, Wo, xb, wqkvb, wob,
                                             ctab, stab);
  gemm_qk<<<512, 512, 0, stream>>>(xb, wqkvb, Qb, Kb, 2048, ctab, stab);
  gemm_v<<<256, 512, 0, stream>>>(xb, wqkvb + (size_t)4096 * 2048, Vt, 2048);
  attn_fwd<<<dim3(32, 16), 256, 0, stream>>>(Qb, Kb, Vt, Ao);
  gemm_o<<<256, 512, 0, stream>>>(Ao, wob, (float*)d_out, 2048, 2048);
}

// Round 21
// 257.550 us; speedup vs baseline: 1.0063x; 1.0063x over previous
//
#include <hip/hip_runtime.h>
#include <stdint.h>

// FINAL (R18 config, session-best 256.9us): cvt(fp32->bf16, + RoPE tables)
//   -> gemm_qk: x@[Wq;Wk] -> Q,K [BH][S][128], 256^2 tiles, 4-deep ring (128KB),
//      grid 256, RoPE fused in epilogue (pair col d^64 = wave w^1 via dead 64KB As ring;
//      Q also scaled 1/sqrt(128)).
//   -> gemm_v : x@Wv -> V^T [BH][128][S] (128x256, 4-deep ring, grid 256)
//   -> attn_fwd (R14-exact, ~100us floor): QBLK=64, 4 waves, pairs (p,31-p),
//      grid (bh=32,pair=16)=512, 75KB LDS -> 2 blocks/CU, XCD-aligned, counted vmcnt,
//      defer-max; Q pre-roped+scaled.
//   -> gemm_o : out-proj on deep 128x256 engine, fp32 epilogue, grid 256.

#define SCALE_Q 0.08838834764831845f

typedef short bf16x8 __attribute__((ext_vector_type(8)));
typedef float f32x4 __attribute__((ext_vector_type(4)));
typedef unsigned short u16x4v __attribute__((ext_vector_type(4)));
typedef unsigned short u16x8v __attribute__((ext_vector_type(8)));

__device__ __forceinline__ unsigned short f2bf(float f) {
  unsigned u = __float_as_uint(f);
  return (unsigned short)((u + 0x7FFFu + ((u >> 16) & 1u)) >> 16);  // RNE
}
__device__ __forceinline__ float bf2f(unsigned short h) {
  return __uint_as_float(((unsigned)h) << 16);
}
__device__ __forceinline__ void gld16(void* lds, const void* g) {
  __builtin_amdgcn_global_load_lds(
      (const __attribute__((address_space(1))) unsigned int*)g,
      (__attribute__((address_space(3))) unsigned int*)lds, 16, 0, 0);
}

// -------- fp32 -> bf16 conversion (regions 0-4) + RoPE tables (region 5) --------
__global__ __launch_bounds__(256) void cvt_all(
    const float* __restrict__ x, const float* __restrict__ wq,
    const float* __restrict__ wk, const float* __restrict__ wv,
    const float* __restrict__ wo,
    unsigned short* __restrict__ xb, unsigned short* __restrict__ wqkv,
    unsigned short* __restrict__ wob,
    float* __restrict__ ct, float* __restrict__ st) {
  int r = blockIdx.y;
  if (r == 5) {  // ct/st[s*64+j] = cos/sin(s * 10000^(-j/64))
    int id = blockIdx.x * 256 + threadIdx.x;
    if (id < 131072) {
      int s = id >> 6, j = id & 63;
      float inv = __powf(10000.0f, -(float)j * (1.0f / 64.0f));
      float a = (float)s * inv;
      ct[id] = __cosf(a);
      st[id] = __sinf(a);
    }
    return;
  }
  size_t i = ((size_t)blockIdx.x * 256 + threadIdx.x) * 8;
  const float* src; unsigned short* dst; size_t n;
  if (r == 0)      { src = x;  dst = xb;             n = 8388608; }
  else if (r == 1) { src = wq; dst = wqkv;           n = 4194304; }
  else if (r == 2) { src = wk; dst = wqkv + 4194304; n = 4194304; }
  else if (r == 3) { src = wv; dst = wqkv + 8388608; n = 4194304; }
  else             { src = wo; dst = wob;            n = 4194304; }
  if (i >= n) return;
  float4 a = *(const float4*)(src + i);
  float4 b = *(const float4*)(src + i + 4);
  u16x8v o;
  o[0] = f2bf(a.x); o[1] = f2bf(a.y); o[2] = f2bf(a.z); o[3] = f2bf(a.w);
  o[4] = f2bf(b.x); o[5] = f2bf(b.y); o[6] = f2bf(b.z); o[7] = f2bf(b.w);
  *(u16x8v*)(dst + i) = o;
}

// ---------------- gemm_qk: 256x256x32, 4-deep ring (128KB), grid 16x16=256 --------------
// Epilogue fuses RoPE: partner of col d is d^64 = same lane, wave w^1 (wn bit0).
// Exchange fp32 acc slices through dead ring LDS As (64KB >= 32KB needed).
__global__ __launch_bounds__(512, 2) void gemm_qk(
    const unsigned short* __restrict__ A, const unsigned short* __restrict__ B,
    unsigned short* __restrict__ Qo, unsigned short* __restrict__ Ko, int Kd,
    const float* __restrict__ ctab, const float* __restrict__ stab) {
  __shared__ unsigned short As[4][128 * 64];   // 4 x 16KB
  __shared__ unsigned short Bs[4][128 * 64];   // 4 x 16KB
  const int t = threadIdx.x;
  const int lane = t & 63, w = t >> 6;
  const int g = lane >> 4, c15 = lane & 15;
  const int wm = w >> 2, wn = w & 3;

  const int chunk = (int)blockIdx.x & 7;
  const int idx = (int)blockIdx.x >> 3;       // 0..31
  const int row = idx & 15;
  const int col = chunk * 2 + (idx >> 4);
  const int brow = row * 256, bcol = col * 256;

  const int l = t >> 3;
  const int lg = (t & 7) ^ (l & 7);
  const unsigned short* srcA = A + (size_t)(brow + l + ((lg >> 2) << 7)) * Kd + (lg & 3) * 8;
  const unsigned short* srcB = B + (size_t)(bcol + l + ((lg >> 2) << 7)) * Kd + (lg & 3) * 8;

  auto stage = [&](int kt) {
    const int buf = kt & 3;
    const unsigned short* a = srcA + kt * 32;
    const unsigned short* b = srcB + kt * 32;
    gld16((char*)As[buf] + t * 16, a);
    gld16((char*)As[buf] + 8192 + t * 16, a + (size_t)64 * Kd);
    gld16((char*)Bs[buf] + t * 16, b);
    gld16((char*)Bs[buf] + 8192 + t * 16, b + (size_t)64 * Kd);
  };

  const int aoff = c15 * 128 + ((((wm << 2) | g) ^ (c15 & 7)) << 4);
  const int boff = ((wn & 1) << 13) + c15 * 128 + (((((wn >> 1) << 2) | g) ^ (c15 & 7)) << 4);

  f32x4 zero4 = {0.f, 0.f, 0.f, 0.f};
  f32x4 acc[8][4];
#pragma unroll
  for (int a_ = 0; a_ < 8; ++a_)
#pragma unroll
    for (int b_ = 0; b_ < 4; ++b_) acc[a_][b_] = zero4;

  const int nk = Kd >> 5;  // 64
  stage(0); stage(1); stage(2);
  asm volatile("s_waitcnt vmcnt(8)" ::: "memory");
  __builtin_amdgcn_s_barrier();

  for (int kt = 0; kt < nk; ++kt) {
    const char* ab = (const char*)As[kt & 3];
    const char* bb = (const char*)Bs[kt & 3];
    bf16x8 bfv[4], af0[4], af1[4];
#pragma unroll
    for (int nj = 0; nj < 4; ++nj) bfv[nj] = *(const bf16x8*)(bb + boff + nj * 2048);
#pragma unroll
    for (int mi = 0; mi < 4; ++mi) af0[mi] = *(const bf16x8*)(ab + aoff + mi * 2048);
    __builtin_amdgcn_sched_barrier(0);
#pragma unroll
    for (int mi = 0; mi < 4; ++mi) af1[mi] = *(const bf16x8*)(ab + aoff + (mi + 4) * 2048);
    if (kt + 3 < nk) stage(kt + 3);
    asm volatile("s_waitcnt lgkmcnt(4)" ::: "memory");
    __builtin_amdgcn_sched_barrier(0);
    __builtin_amdgcn_s_setprio(1);
#pragma unroll
    for (int mi = 0; mi < 4; ++mi)
#pragma unroll
      for (int nj = 0; nj < 4; ++nj)
        acc[mi][nj] = __builtin_amdgcn_mfma_f32_16x16x32_bf16(
            af0[mi], bfv[nj], acc[mi][nj], 0, 0, 0);
    __builtin_amdgcn_s_setprio(0);
    asm volatile("s_waitcnt lgkmcnt(0)" ::: "memory");
    __builtin_amdgcn_sched_barrier(0);
    __builtin_amdgcn_s_setprio(1);
#pragma unroll
    for (int mi = 0; mi < 4; ++mi)
#pragma unroll
      for (int nj = 0; nj < 4; ++nj)
        acc[mi + 4][nj] = __builtin_amdgcn_mfma_f32_16x16x32_bf16(
            af1[mi], bfv[nj], acc[mi + 4][nj], 0, 0, 0);
    __builtin_amdgcn_s_setprio(0);
    if (kt + 3 < nk) {
      asm volatile("s_waitcnt vmcnt(8)" ::: "memory");
    } else if (kt + 2 < nk) {
      asm volatile("s_waitcnt vmcnt(4)" ::: "memory");
    } else if (kt + 1 < nk) {
      asm volatile("s_waitcnt vmcnt(0)" ::: "memory");
    }
    __builtin_amdgcn_s_barrier();
  }

  // Epilogue with fused RoPE. Ring As (64KB) dead -> fp32 exchange
  // [8 w][4 nj][4 i][64 lane] = 32KB, per-mi slices.
  float* xch = (float*)As;
#pragma unroll
  for (int mi = 0; mi < 8; ++mi) {
#pragma unroll
    for (int nj = 0; nj < 4; ++nj)
#pragma unroll
      for (int i = 0; i < 4; ++i)
        xch[w * 1024 + nj * 256 + i * 64 + lane] = acc[mi][nj][i];
    asm volatile("s_waitcnt lgkmcnt(0)" ::: "memory");
    __builtin_amdgcn_s_barrier();               // slice visible to partner wave
    int row0 = brow + wm * 128 + mi * 16 + g * 4;
    int s0 = row0 & 2047;
#pragma unroll
    for (int nj = 0; nj < 4; ++nj) {
      int colc = bcol + wn * 64 + nj * 16 + c15;
      int which = colc >> 11;           // 0=Q 1=K
      int hc = colc & 2047;
      int bh = ((row0 >> 11) << 4) + (hc >> 7);
      int d = hc & 127;
      int j6 = d & 63;
      float sgn = (d & 64) ? 1.0f : -1.0f;   // out_lo = v*c - hi*s ; out_hi = v*c + lo*s
      float scl = which ? 1.0f : SCALE_Q;
      unsigned short* dst = (which ? Ko : Qo) + ((size_t)bh * 2048 + s0) * 128 + d;
#pragma unroll
      for (int i = 0; i < 4; ++i) {
        float c = ctab[(size_t)(s0 + i) * 64 + j6];
        float sn = stab[(size_t)(s0 + i) * 64 + j6];
        float v = acc[mi][nj][i];
        float pv = xch[(w ^ 1) * 1024 + nj * 256 + i * 64 + lane];
        dst[(size_t)i * 128] = f2bf((v * c + sgn * pv * sn) * scl);
      }
    }
    asm volatile("s_waitcnt lgkmcnt(0)" ::: "memory");
    __builtin_amdgcn_s_barrier();               // reads done before next slice overwrite
  }
}

// ---------------- gemm_v: 128x256x32, 4-deep ring (96KB), grid 32x8=256 ----------------
__global__ __launch_bounds__(512, 2) void gemm_v(
    const unsigned short* __restrict__ A, const unsigned short* __restrict__ B,
    unsigned short* __restrict__ Vt, int Kd) {
  __shared__ unsigned short As[4][64 * 64];    // 4 x 8KB
  __shared__ unsigned short Bs[4][128 * 64];   // 4 x 16KB
  const int t = threadIdx.x;
  const int lane = t & 63, w = t >> 6;
  const int g = lane >> 4, c15 = lane & 15;
  const int wm = w >> 2, wn = w & 3;

  const int chunk = (int)blockIdx.x & 7;
  const int idx = (int)blockIdx.x >> 3;       // 0..31
  const int row = chunk * 4 + (idx >> 3);
  const int col = idx & 7;
  const int brow = row * 128, bcol = col * 256;

  const int l = t >> 3;
  const int lg = (t & 7) ^ (l & 7);
  const unsigned short* srcA = A + (size_t)(brow + l + ((lg >> 2) << 6)) * Kd + (lg & 3) * 8;
  const unsigned short* srcB = B + (size_t)(bcol + l + ((lg >> 2) << 7)) * Kd + (lg & 3) * 8;

  auto stage = [&](int kt) {
    const int buf = kt & 3;
    const unsigned short* a = srcA + kt * 32;
    const unsigned short* b = srcB + kt * 32;
    gld16((char*)As[buf] + t * 16, a);
    gld16((char*)Bs[buf] + t * 16, b);
    gld16((char*)Bs[buf] + 8192 + t * 16, b + (size_t)64 * Kd);
  };

  const int aoff = c15 * 128 + ((((wm << 2) | g) ^ (c15 & 7)) << 4);
  const int boff = ((wn & 1) << 13) + c15 * 128 + (((((wn >> 1) << 2) | g) ^ (c15 & 7)) << 4);

  f32x4 zero4 = {0.f, 0.f, 0.f, 0.f};
  f32x4 acc[4][4];
#pragma unroll
  for (int a_ = 0; a_ < 4; ++a_)
#pragma unroll
    for (int b_ = 0; b_ < 4; ++b_) acc[a_][b_] = zero4;

  const int nk = Kd >> 5;  // 64
  stage(0); stage(1); stage(2);
  asm volatile("s_waitcnt vmcnt(6)" ::: "memory");
  __builtin_amdgcn_s_barrier();

  for (int kt = 0; kt < nk; ++kt) {
    const char* ab = (const char*)As[kt & 3];
    const char* bb = (const char*)Bs[kt & 3];
    bf16x8 bfv[4], af0[2], af1[2];
#pragma unroll
    for (int nj = 0; nj < 4; ++nj) bfv[nj] = *(const bf16x8*)(bb + boff + nj * 2048);
#pragma unroll
    for (int mi = 0; mi < 2; ++mi) af0[mi] = *(const bf16x8*)(ab + aoff + mi * 2048);
    __builtin_amdgcn_sched_barrier(0);
#pragma unroll
    for (int mi = 0; mi < 2; ++mi) af1[mi] = *(const bf16x8*)(ab + aoff + (mi + 2) * 2048);
    if (kt + 3 < nk) stage(kt + 3);
    asm volatile("s_waitcnt lgkmcnt(2)" ::: "memory");
    __builtin_amdgcn_sched_barrier(0);
    __builtin_amdgcn_s_setprio(1);
#pragma unroll
    for (int mi = 0; mi < 2; ++mi)
#pragma unroll
      for (int nj = 0; nj < 4; ++nj)
        acc[mi][nj] = __builtin_amdgcn_mfma_f32_16x16x32_bf16(
            af0[mi], bfv[nj], acc[mi][nj], 0, 0, 0);
    __builtin_amdgcn_s_setprio(0);
    asm volatile("s_waitcnt lgkmcnt(0)" ::: "memory");
    __builtin_amdgcn_sched_barrier(0);
    __builtin_amdgcn_s_setprio(1);
#pragma unroll
    for (int mi = 0; mi < 2; ++mi)
#pragma unroll
      for (int nj = 0; nj < 4; ++nj)
        acc[mi + 2][nj] = __builtin_amdgcn_mfma_f32_16x16x32_bf16(
            af1[mi], bfv[nj], acc[mi + 2][nj], 0, 0, 0);
    __builtin_amdgcn_s_setprio(0);
    if (kt + 3 < nk) {
      asm volatile("s_waitcnt vmcnt(6)" ::: "memory");
    } else if (kt + 3 == nk) {
      asm volatile("s_waitcnt vmcnt(3)" ::: "memory");
    } else if (kt + 2 == nk) {
      asm volatile("s_waitcnt vmcnt(0)" ::: "memory");
    }
    __builtin_amdgcn_s_barrier();
  }

#pragma unroll
  for (int mi = 0; mi < 4; ++mi) {
#pragma unroll
    for (int nj = 0; nj < 4; ++nj) {
      f32x4 v = acc[mi][nj];
      int row0 = brow + wm * 64 + mi * 16 + g * 4;
      int colc = bcol + wn * 64 + nj * 16 + c15;
      int bh = ((row0 >> 11) << 4) + (colc >> 7);
      int d = colc & 127, s0 = row0 & 2047;
      u16x4v pk;
      pk[0] = f2bf(v[0]); pk[1] = f2bf(v[1]); pk[2] = f2bf(v[2]); pk[3] = f2bf(v[3]);
      *(u16x4v*)(Vt + ((size_t)bh * 128 + d) * 2048 + s0) = pk;
    }
  }
}

// ---------------- gemm_o: out-proj, 128x256x32 deep ring, fp32 epilogue, grid 256 -------
__global__ __launch_bounds__(512, 2) void gemm_o(
    const unsigned short* __restrict__ A, const unsigned short* __restrict__ B,
    float* __restrict__ C, int N, int Kd) {
  __shared__ unsigned short As[4][64 * 64];    // 4 x 8KB
  __shared__ unsigned short Bs[4][128 * 64];   // 4 x 16KB
  const int t = threadIdx.x;
  const int lane = t & 63, w = t >> 6;
  const int g = lane >> 4, c15 = lane & 15;
  const int wm = w >> 2, wn = w & 3;

  const int chunk = (int)blockIdx.x & 7;
  const int idx = (int)blockIdx.x >> 3;       // 0..31
  const int row = chunk * 4 + (idx >> 3);
  const int col = idx & 7;
  const int brow = row * 128, bcol = col * 256;

  const int l = t >> 3;
  const int lg = (t & 7) ^ (l & 7);
  const unsigned short* srcA = A + (size_t)(brow + l + ((lg >> 2) << 6)) * Kd + (lg & 3) * 8;
  const unsigned short* srcB = B + (size_t)(bcol + l + ((lg >> 2) << 7)) * Kd + (lg & 3) * 8;

  auto stage = [&](int kt) {
    const int buf = kt & 3;
    const unsigned short* a = srcA + kt * 32;
    const unsigned short* b = srcB + kt * 32;
    gld16((char*)As[buf] + t * 16, a);
    gld16((char*)Bs[buf] + t * 16, b);
    gld16((char*)Bs[buf] + 8192 + t * 16, b + (size_t)64 * Kd);
  };

  const int aoff = c15 * 128 + ((((wm << 2) | g) ^ (c15 & 7)) << 4);
  const int boff = ((wn & 1) << 13) + c15 * 128 + (((((wn >> 1) << 2) | g) ^ (c15 & 7)) << 4);

  f32x4 zero4 = {0.f, 0.f, 0.f, 0.f};
  f32x4 acc[4][4];
#pragma unroll
  for (int a_ = 0; a_ < 4; ++a_)
#pragma unroll
    for (int b_ = 0; b_ < 4; ++b_) acc[a_][b_] = zero4;

  const int nk = Kd >> 5;  // 64
  stage(0); stage(1); stage(2);
  asm volatile("s_waitcnt vmcnt(6)" ::: "memory");
  __builtin_amdgcn_s_barrier();

  for (int kt = 0; kt < nk; ++kt) {
    const char* ab = (const char*)As[kt & 3];
    const char* bb = (const char*)Bs[kt & 3];
    bf16x8 bfv[4], af0[2], af1[2];
#pragma unroll
    for (int nj = 0; nj < 4; ++nj) bfv[nj] = *(const bf16x8*)(bb + boff + nj * 2048);
#pragma unroll
    for (int mi = 0; mi < 2; ++mi) af0[mi] = *(const bf16x8*)(ab + aoff + mi * 2048);
    __builtin_amdgcn_sched_barrier(0);
#pragma unroll
    for (int mi = 0; mi < 2; ++mi) af1[mi] = *(const bf16x8*)(ab + aoff + (mi + 2) * 2048);
    if (kt + 3 < nk) stage(kt + 3);
    asm volatile("s_waitcnt lgkmcnt(2)" ::: "memory");
    __builtin_amdgcn_sched_barrier(0);
    __builtin_amdgcn_s_setprio(1);
#pragma unroll
    for (int mi = 0; mi < 2; ++mi)
#pragma unroll
      for (int nj = 0; nj < 4; ++nj)
        acc[mi][nj] = __builtin_amdgcn_mfma_f32_16x16x32_bf16(
            af0[mi], bfv[nj], acc[mi][nj], 0, 0, 0);
    __builtin_amdgcn_s_setprio(0);
    asm volatile("s_waitcnt lgkmcnt(0)" ::: "memory");
    __builtin_amdgcn_sched_barrier(0);
    __builtin_amdgcn_s_setprio(1);
#pragma unroll
    for (int mi = 0; mi < 2; ++mi)
#pragma unroll
      for (int nj = 0; nj < 4; ++nj)
        acc[mi + 2][nj] = __builtin_amdgcn_mfma_f32_16x16x32_bf16(
            af1[mi], bfv[nj], acc[mi + 2][nj], 0, 0, 0);
    __builtin_amdgcn_s_setprio(0);
    if (kt + 3 < nk) {
      asm volatile("s_waitcnt vmcnt(6)" ::: "memory");
    } else if (kt + 3 == nk) {
      asm volatile("s_waitcnt vmcnt(3)" ::: "memory");
    } else if (kt + 2 == nk) {
      asm volatile("s_waitcnt vmcnt(0)" ::: "memory");
    }
    __builtin_amdgcn_s_barrier();
  }

#pragma unroll
  for (int mi = 0; mi < 4; ++mi) {
#pragma unroll
    for (int nj = 0; nj < 4; ++nj) {
      f32x4 v = acc[mi][nj];
      int row0 = brow + wm * 64 + mi * 16 + g * 4;
      int colc = bcol + wn * 64 + nj * 16 + c15;
#pragma unroll
      for (int i = 0; i < 4; ++i) C[(size_t)(row0 + i) * N + colc] = v[i];
    }
  }
}

// ---------------- attn_fwd (R14 exact; Q pre-roped+scaled by gemm_qk epilogue) ----------
__global__ __launch_bounds__(256, 2) void attn_fwd(
    const unsigned short* __restrict__ Qg, const unsigned short* __restrict__ Kg,
    const unsigned short* __restrict__ Vtg, unsigned short* __restrict__ Og) {
  __shared__ unsigned short Ks[2][64 * 128];   // [kv64][d128] 256B rows, swz ^(row&15)
  __shared__ unsigned short Vs[2][128 * 64];   // [d128][kv64] 128B rows, swz ^(row&7)
  __shared__ unsigned short Pl[4][16 * 88];    // per-wave P buffer
  const int t = threadIdx.x;
  const int lane = t & 63, w = t >> 6;         // w 0..3
  const int g = lane >> 4, c15 = lane & 15;
  const int bh = blockIdx.x;                   // 0..31 -> bid%8 = bh%8 = XCD
  const int pair = blockIdx.y;                 // 0..15
  const int b = bh >> 4, h = bh & 15;

  const int ksrow = t >> 4;                    // 0..15
  const int kssl = (t & 15) ^ (ksrow & 15);
  const unsigned short* kp = Kg + ((size_t)bh * 2048 + ksrow) * 128 + kssl * 8;
  const int vsrow = t >> 3;                    // 0..31
  const int vssl = (t & 7) ^ (vsrow & 7);
  const unsigned short* vp = Vtg + ((size_t)bh * 128 + vsrow) * 2048 + vssl * 8;

  auto stageTile = [&](int buf, int tkv) {     // 8 gld16/thread = 32KB total
#pragma unroll
    for (int c = 0; c < 4; ++c) {
      gld16((char*)Ks[buf] + c * 4096 + t * 16, kp + (size_t)(tkv * 64 + c * 16) * 128);
      gld16((char*)Vs[buf] + c * 4096 + t * 16, vp + (size_t)c * 32 * 2048 + tkv * 64);
    }
  };

  f32x4 zero4 = {0.f, 0.f, 0.f, 0.f};
  f32x4 o[8];
  float mrow[4], lrow[4];
  bf16x8 qf[4];

  auto loadQ = [&](int qb) {
    const unsigned short* qp =
        Qg + ((size_t)bh * 2048 + qb * 64 + w * 16 + c15) * 128 + g * 8;
#pragma unroll
    for (int kf = 0; kf < 4; ++kf) qf[kf] = *(const bf16x8*)(qp + kf * 32);
#pragma unroll
    for (int db = 0; db < 8; ++db) o[db] = zero4;
#pragma unroll
    for (int i = 0; i < 4; ++i) { mrow[i] = -1e30f; lrow[i] = 0.f; }
  };

  auto computeTile = [&](int buf, int qb, int tkv) {
    const int qrow = qb * 64 + w * 16;
    f32x4 sv[4];
    __builtin_amdgcn_s_setprio(1);
#pragma unroll
    for (int cb2 = 0; cb2 < 4; ++cb2) {
      f32x4 z = zero4;
#pragma unroll
      for (int kf = 0; kf < 4; ++kf) {
        int rowk = cb2 * 16 + c15;
        int p = (kf * 4 + g) ^ c15;
        bf16x8 kfr = *(const bf16x8*)((const char*)Ks[buf] + rowk * 256 + p * 16);
        z = __builtin_amdgcn_mfma_f32_16x16x32_bf16(qf[kf], kfr, z, 0, 0, 0);
      }
      sv[cb2] = z;
    }
    __builtin_amdgcn_s_setprio(0);
    if (tkv == qb) {  // diagonal tile causal mask
#pragma unroll
      for (int cb2 = 0; cb2 < 4; ++cb2)
#pragma unroll
        for (int i = 0; i < 4; ++i) {
          int colk = tkv * 64 + cb2 * 16 + c15;
          int rq = qrow + g * 4 + i;
          if (colk > rq) sv[cb2][i] = -1e30f;
        }
    }
    float pmx[4];
#pragma unroll
    for (int i = 0; i < 4; ++i)
      pmx[i] = fmaxf(fmaxf(sv[0][i], sv[1][i]), fmaxf(sv[2][i], sv[3][i]));
#pragma unroll
    for (int dd = 1; dd < 16; dd <<= 1)
#pragma unroll
      for (int i = 0; i < 4; ++i) pmx[i] = fmaxf(pmx[i], __shfl_xor(pmx[i], dd));
    int grow = 0;
#pragma unroll
    for (int i = 0; i < 4; ++i) grow |= (pmx[i] > mrow[i] + 8.0f) ? 1 : 0;
    if (__any(grow)) {  // defer-max (T13)
#pragma unroll
      for (int i = 0; i < 4; ++i) {
        float nm = fmaxf(mrow[i], pmx[i]);
        float sc = __expf(mrow[i] - nm);
        mrow[i] = nm;
        lrow[i] *= sc;
#pragma unroll
        for (int db = 0; db < 8; ++db) o[db][i] *= sc;
      }
    }
    float psum[4] = {0.f, 0.f, 0.f, 0.f};
#pragma unroll
    for (int cb2 = 0; cb2 < 4; ++cb2)
#pragma unroll
      for (int i = 0; i < 4; ++i) {
        float e = __expf(sv[cb2][i] - mrow[i]);
        sv[cb2][i] = e;
        psum[i] += e;
      }
#pragma unroll
    for (int dd = 1; dd < 16; dd <<= 1)
#pragma unroll
      for (int i = 0; i < 4; ++i) psum[i] += __shfl_xor(psum[i], dd);
#pragma unroll
    for (int i = 0; i < 4; ++i) lrow[i] += psum[i];

    unsigned short* pw = &Pl[w][0];
#pragma unroll
    for (int cb2 = 0; cb2 < 4; ++cb2)
#pragma unroll
      for (int i = 0; i < 4; ++i)
        pw[(g * 4 + i) * 88 + cb2 * 16 + c15] = f2bf(sv[cb2][i]);
    bf16x8 pf[2];
#pragma unroll
    for (int kb = 0; kb < 2; ++kb)
      pf[kb] = *(const bf16x8*)((const char*)pw + c15 * 176 + kb * 64 + g * 16);

    __builtin_amdgcn_s_setprio(1);
#pragma unroll
    for (int db = 0; db < 8; ++db) {
#pragma unroll
      for (int kb = 0; kb < 2; ++kb) {
        int rowv = db * 16 + c15;
        int p = (kb * 4 + g) ^ (c15 & 7);
        bf16x8 vfr = *(const bf16x8*)((const char*)Vs[buf] + rowv * 128 + p * 16);
        o[db] = __builtin_amdgcn_mfma_f32_16x16x32_bf16(pf[kb], vfr, o[db], 0, 0, 0);
      }
    }
    __builtin_amdgcn_s_setprio(0);
  };

  auto writeO = [&](int qb) {
    float linv[4];
#pragma unroll
    for (int i = 0; i < 4; ++i) linv[i] = 1.0f / lrow[i];
#pragma unroll
    for (int db = 0; db < 8; ++db)
#pragma unroll
      for (int i = 0; i < 4; ++i) {
        int q = qb * 64 + w * 16 + g * 4 + i;
        Og[((size_t)(b * 2048 + q)) * 2048 + h * 128 + db * 16 + c15] =
            f2bf(o[db][i] * linv[i]);
      }
  };

  const int qbA = pair, qbB = 31 - pair;       // 64-row q-blocks
  const int ntA = qbA + 1, ntB = qbB + 1;      // 33 tiles total, uniform
  int cur = 0;

  stageTile(0, 0);
  loadQ(qbA);
  for (int tkv = 0; tkv < ntA; ++tkv) {
    if (tkv + 1 < ntA) stageTile(cur ^ 1, tkv + 1);
    else               stageTile(cur ^ 1, 0);          // first tile of half B
    asm volatile("s_waitcnt vmcnt(8)" ::: "memory");   // current buf landed
    __builtin_amdgcn_s_barrier();
    computeTile(cur, qbA, tkv);
    __builtin_amdgcn_s_barrier();                      // close reads of buf[cur]
    cur ^= 1;
  }
  writeO(qbA);
  loadQ(qbB);
  for (int tkv = 0; tkv < ntB; ++tkv) {
    if (tkv + 1 < ntB) {
      stageTile(cur ^ 1, tkv + 1);
      asm volatile("s_waitcnt vmcnt(8)" ::: "memory");
    } else {
      asm volatile("s_waitcnt vmcnt(0)" ::: "memory");
    }
    __builtin_amdgcn_s_barrier();
    computeTile(cur, qbB, tkv);
    __builtin_amdgcn_s_barrier();
    cur ^= 1;
  }
  writeO(qbB);
}

extern "C" void kernel_launch(void* const* d_in, const int* in_sizes, int n_in,
                              void* d_out, int out_size, void* d_ws, size_t ws_size,
                              hipStream_t stream) {
  const float* x  = (const float*)d_in[0];
  const float* Wq = (const float*)d_in[1];
  const float* Wk = (const float*)d_in[2];
  const float* Wv = (const float*)d_in[3];
  const float* Wo = (const float*)d_in[4];
  char* p = (char*)d_ws;
  unsigned short* xb    = (unsigned short*)p;                 // 16 MB (reused as Ao)
  unsigned short* wqkvb = (unsigned short*)(p + 16777216);    // 24 MB
  unsigned short* wob   = (unsigned short*)(p + 41943040);    //  8 MB
  unsigned short* Qb    = (unsigned short*)(p + 50331648);    // 16 MB
  unsigned short* Kb    = (unsigned short*)(p + 67108864);    // 16 MB
  unsigned short* Vt    = (unsigned short*)(p + 83886080);    // 16 MB
  float* ctab           = (float*)(p + 100663296);            // 0.5 MB
  float* stab           = (float*)(p + 101187584);            // 0.5 MB -> end 101711872
  unsigned short* Ao = xb;  // xb dead after QKV gemms

  cvt_all<<<dim3(4096, 6), 256, 0, stream>>>(x, Wq, Wk, Wv, Wo, xb, wqkvb, wob,
                                             ctab, stab);
  gemm_qk<<<256, 512, 0, stream>>>(xb, wqkvb, Qb, Kb, 2048, ctab, stab);
  gemm_v<<<256, 512, 0, stream>>>(xb, wqkvb + (size_t)4096 * 2048, Vt, 2048);
  attn_fwd<<<dim3(32, 16), 256, 0, stream>>>(Qb, Kb, Vt, Ao);
  gemm_o<<<256, 512, 0, stream>>>(Ao, wob, (float*)d_out, 2048, 2048);
}